// Round 2
// baseline (87.478 us; speedup 1.0000x reference)
//
#include <hip/hip_runtime.h>
#include <hip/hip_bf16.h>
#include <math.h>

// ROI adaptive max-pool to 7x7 (torch adaptive_max_pool2d bin semantics).
// feature_map: [B=2, C=256, H=50, W=50] fp32
// rois:        [R=192, 5] int32 (batch, x1, y1, x2, y2), 1<=w,h, x2<=W, y2<=H
// out:         [R, C, 7, 7] fp32
//
// Round 2 structure: one WAVE per (roi, channel). lane = column offset
// (x = x1 + lane, w <= 50 <= 64), so each ROI row is ONE coalesced
// global_load_dword across the wave instead of ~13 divergent scalar loads
// per thread (~22x fewer VMEM instructions). The wave computes 7 row-bin
// column-maxes (tw[i][lane]) in registers, drops them to LDS, then 49
// threads per channel reduce the column bins and store 196 contiguous
// output floats per block.
//
// Block = 256 threads = 4 waves = 4 consecutive channels of the SAME roi,
// so all waves have identical trip counts and __syncthreads is free.

#define OUT_N 7
#define CPB 4          // channels (waves) per block
#define LDS_W 65       // pad 64->65 to spread epilogue LDS banks

__global__ __launch_bounds__(256) void roicrop_kernel(
    const float* __restrict__ fm,
    const int* __restrict__ rois,
    float* __restrict__ out,
    int R, int C, int H, int W)
{
    __shared__ float tw[CPB][OUT_N][LDS_W];

    const int lane = threadIdx.x & 63;
    const int wave = threadIdx.x >> 6;           // 0..3
    const int cg_per_r = C / CPB;                // 64
    const int r  = blockIdx.x / cg_per_r;
    const int cg = blockIdx.x % cg_per_r;
    const int c  = cg * CPB + wave;

    const int* roi = rois + r * 5;
    const int b  = roi[0];
    const int x1 = roi[1];
    const int y1 = roi[2];
    const int x2 = roi[3];
    const int y2 = roi[4];
    const int h = y2 - y1;
    const int w = x2 - x1;

    // lane -> column x1+lane; clamp lanes >= w to a safe in-bounds column
    // (their tw values are never read: col bins only cover dx < w).
    int x = x1 + lane;
    if (lane >= w) x = x1;
    const float* col = fm + (size_t)(b * C + c) * (size_t)(H * W) + x;

    #pragma unroll
    for (int i = 0; i < OUT_N; ++i) {
        const int ys = y1 + (i * h) / OUT_N;
        const int ye = y1 + ((i + 1) * h + OUT_N - 1) / OUT_N;
        float m = -INFINITY;
        const float* p = col + (size_t)ys * W;
        for (int y = ys; y < ye; ++y) {
            m = fmaxf(m, *p);
            p += W;
        }
        tw[wave][i][lane] = m;
    }
    __syncthreads();

    const int t = threadIdx.x;
    if (t < CPB * OUT_N * OUT_N) {               // 196 threads
        const int wc = t / (OUT_N * OUT_N);      // channel-in-block
        const int l  = t % (OUT_N * OUT_N);      // i*7+j
        const int i  = l / OUT_N;
        const int j  = l % OUT_N;
        const int xs = (j * w) / OUT_N;                      // rel. to x1
        const int xe = ((j + 1) * w + OUT_N - 1) / OUT_N;
        float m = -INFINITY;
        for (int dx = xs; dx < xe; ++dx) {
            m = fmaxf(m, tw[wc][i][dx]);
        }
        const int cc = cg * CPB + wc;
        out[((size_t)r * C + cc) * (OUT_N * OUT_N) + l] = m;
    }
}

extern "C" void kernel_launch(void* const* d_in, const int* in_sizes, int n_in,
                              void* d_out, int out_size, void* d_ws, size_t ws_size,
                              hipStream_t stream)
{
    const float* fm = (const float*)d_in[0];
    const int* rois = (const int*)d_in[1];
    float* out      = (float*)d_out;

    const int R = in_sizes[1] / 5;                        // 192
    const int C = out_size / (R * OUT_N * OUT_N);         // 256
    const int H = 50;
    const int W = 50;

    const int grid = R * (C / CPB);                       // 12288
    roicrop_kernel<<<grid, 256, 0, stream>>>(fm, rois, out, R, C, H, W);
}

// Round 3
// 78.238 us; speedup vs baseline: 1.1181x; 1.1181x over previous
//
#include <hip/hip_runtime.h>
#include <hip/hip_bf16.h>
#include <math.h>

// ROI adaptive max-pool to 7x7 (torch adaptive_max_pool2d bin semantics).
// feature_map: [B=2, C=256, H=50, W=50] fp32
// rois:        [R=192, 5] int32 (batch, x1, y1, x2, y2), 1<=w,h, x2<=W, y2<=H
// out:         [R, C, 7, 7] fp32
//
// Round 3: attack memory-level parallelism. R2 was a serial dependent chain
// (one outstanding L2 load per wave). Now each wave handles TWO channels
// (independent load chains) and the per-bin row loop is unrolled by 2 ->
// up to 4 independent loads in flight per wave (MLP x4). Lane = column
// (x1+lane, w<=50<=64) so every row read is one coalesced load.
// Block = 4 waves x 2ch = 8 channels of the same roi; grid = 192*32 = 6144.

#define OUT_N 7
#define CPB 8          // channels per block (4 waves x 2)
#define LDS_W 65       // pad 64->65 to spread epilogue LDS banks

__global__ __launch_bounds__(256) void roicrop_kernel(
    const float* __restrict__ fm,
    const int* __restrict__ rois,
    float* __restrict__ out,
    int R, int C, int H, int W)
{
    __shared__ float tw[CPB][OUT_N][LDS_W];

    const int lane = threadIdx.x & 63;
    const int wave = threadIdx.x >> 6;           // 0..3
    const int cg_per_r = C / CPB;                // 32
    const int r  = blockIdx.x / cg_per_r;
    const int cg = blockIdx.x % cg_per_r;
    const int c0 = cg * CPB + wave * 2;          // this wave's channel pair

    const int* roi = rois + r * 5;
    const int b  = roi[0];
    const int x1 = roi[1];
    const int y1 = roi[2];
    const int x2 = roi[3];
    const int y2 = roi[4];
    const int h = y2 - y1;
    const int w = x2 - x1;

    // lane -> column x1+lane; clamp lanes >= w to x1 (values never read:
    // column bins only cover dx < w). Max col = x2-1 <= 49, in-plane.
    int x = x1 + lane;
    if (lane >= w) x = x1;
    const size_t plane = (size_t)(H * W);
    const float* colA = fm + (size_t)(b * C + c0)     * plane + x;
    const float* colB = fm + (size_t)(b * C + c0 + 1) * plane + x;

    #pragma unroll
    for (int i = 0; i < OUT_N; ++i) {
        const int ys = y1 + (i * h) / OUT_N;
        const int ye = y1 + ((i + 1) * h + OUT_N - 1) / OUT_N;
        const int hb = ye - ys;
        const float* pa = colA + (size_t)ys * W;
        const float* pb = colB + (size_t)ys * W;
        float ma = -INFINITY, mb = -INFINITY;
        int k = 0;
        for (; k + 1 < hb; k += 2) {
            // 4 independent loads in flight
            float a0 = pa[0];
            float a1 = pa[W];
            float b0 = pb[0];
            float b1 = pb[W];
            pa += 2 * W;
            pb += 2 * W;
            ma = fmaxf(ma, fmaxf(a0, a1));
            mb = fmaxf(mb, fmaxf(b0, b1));
        }
        if (k < hb) {
            ma = fmaxf(ma, pa[0]);
            mb = fmaxf(mb, pb[0]);
        }
        tw[wave * 2 + 0][i][lane] = ma;
        tw[wave * 2 + 1][i][lane] = mb;
    }
    __syncthreads();

    // Epilogue: CPB*49 = 392 outputs, 256 threads -> 2 rounds.
    const int t = threadIdx.x;
    #pragma unroll
    for (int o = t; o < CPB * OUT_N * OUT_N; o += 256) {
        const int wc = o / (OUT_N * OUT_N);      // channel-in-block
        const int l  = o % (OUT_N * OUT_N);      // i*7+j
        const int i  = l / OUT_N;
        const int j  = l % OUT_N;
        const int xs = (j * w) / OUT_N;                     // rel. to x1
        const int xe = ((j + 1) * w + OUT_N - 1) / OUT_N;
        float m = -INFINITY;
        for (int dx = xs; dx < xe; ++dx) {
            m = fmaxf(m, tw[wc][i][dx]);
        }
        const int cc = cg * CPB + wc;
        out[((size_t)r * C + cc) * (OUT_N * OUT_N) + l] = m;
    }
}

extern "C" void kernel_launch(void* const* d_in, const int* in_sizes, int n_in,
                              void* d_out, int out_size, void* d_ws, size_t ws_size,
                              hipStream_t stream)
{
    const float* fm = (const float*)d_in[0];
    const int* rois = (const int*)d_in[1];
    float* out      = (float*)d_out;

    const int R = in_sizes[1] / 5;                        // 192
    const int C = out_size / (R * OUT_N * OUT_N);         // 256
    const int H = 50;
    const int W = 50;

    const int grid = R * (C / CPB);                       // 6144
    roicrop_kernel<<<grid, 256, 0, stream>>>(fm, rois, out, R, C, H, W);
}

// Round 4
// 77.640 us; speedup vs baseline: 1.1267x; 1.0077x over previous
//
#include <hip/hip_runtime.h>
#include <hip/hip_bf16.h>
#include <math.h>

// ROI adaptive max-pool to 7x7 (torch adaptive_max_pool2d bin semantics).
// feature_map: [B=2, C=256, H=50, W=50] fp32
// rois:        [R=192, 5] int32 (batch, x1, y1, x2, y2), 1<=w,h, x2<=W, y2<=H
// out:         [R, C, 7, 7] fp32
//
// Round 4: maximize memory-level parallelism. Each wave handles FOUR
// channels (4 independent load chains) and the per-bin row loop is
// unrolled by 2 -> up to 8 independent loads in flight per wave.
// Lane = column (x1+lane, w<=50<=64): every ROI row is one coalesced load.
// Block = 4 waves x 4ch = 16 channels of the same roi; grid = 192*16 = 3072
// (12 blocks/CU). Row-bin column-maxes go to LDS; 784-output epilogue
// reduces column bins and stores contiguously.

#define OUT_N 7
#define WPB 4                 // waves per block
#define CHW 4                 // channels per wave
#define CPB (WPB * CHW)       // 16 channels per block
#define LDS_W 65              // pad 64->65 to spread epilogue LDS banks

__global__ __launch_bounds__(256) void roicrop_kernel(
    const float* __restrict__ fm,
    const int* __restrict__ rois,
    float* __restrict__ out,
    int R, int C, int H, int W)
{
    __shared__ float tw[CPB][OUT_N][LDS_W];   // 29.1 KB

    const int lane = threadIdx.x & 63;
    const int wave = threadIdx.x >> 6;        // 0..3
    const int cg_per_r = C / CPB;             // 16
    const int r  = blockIdx.x / cg_per_r;
    const int cg = blockIdx.x % cg_per_r;
    const int c0 = cg * CPB + wave * CHW;     // this wave's first channel

    const int* roi = rois + r * 5;
    const int b  = roi[0];
    const int x1 = roi[1];
    const int y1 = roi[2];
    const int x2 = roi[3];
    const int y2 = roi[4];
    const int h = y2 - y1;
    const int w = x2 - x1;

    // lane -> column x1+lane; clamp lanes >= w to x1 (their tw values are
    // never read: column bins only cover dx < w). Max col x2-1 <= 49.
    int x = x1 + lane;
    if (lane >= w) x = x1;
    const size_t plane = (size_t)(H * W);

    const float* col[CHW];
    #pragma unroll
    for (int cc = 0; cc < CHW; ++cc) {
        col[cc] = fm + (size_t)(b * C + c0 + cc) * plane + x;
    }

    #pragma unroll
    for (int i = 0; i < OUT_N; ++i) {
        const int ys = y1 + (i * h) / OUT_N;
        const int ye = y1 + ((i + 1) * h + OUT_N - 1) / OUT_N;
        const int hb = ye - ys;

        const float* p[CHW];
        float m[CHW];
        #pragma unroll
        for (int cc = 0; cc < CHW; ++cc) {
            p[cc] = col[cc] + (size_t)ys * W;
            m[cc] = -INFINITY;
        }

        int k = 0;
        for (; k + 1 < hb; k += 2) {
            // 8 independent loads in flight
            float v0[CHW], v1[CHW];
            #pragma unroll
            for (int cc = 0; cc < CHW; ++cc) {
                v0[cc] = p[cc][0];
                v1[cc] = p[cc][W];
                p[cc] += 2 * W;
            }
            #pragma unroll
            for (int cc = 0; cc < CHW; ++cc) {
                m[cc] = fmaxf(m[cc], fmaxf(v0[cc], v1[cc]));
            }
        }
        if (k < hb) {
            float v0[CHW];
            #pragma unroll
            for (int cc = 0; cc < CHW; ++cc) v0[cc] = p[cc][0];
            #pragma unroll
            for (int cc = 0; cc < CHW; ++cc) m[cc] = fmaxf(m[cc], v0[cc]);
        }

        #pragma unroll
        for (int cc = 0; cc < CHW; ++cc) {
            tw[wave * CHW + cc][i][lane] = m[cc];
        }
    }
    __syncthreads();

    // Epilogue: CPB*49 = 784 outputs, 256 threads -> 4 rounds (last partial).
    const int t = threadIdx.x;
    for (int o = t; o < CPB * OUT_N * OUT_N; o += 256) {
        const int wc = o / (OUT_N * OUT_N);   // channel-in-block
        const int l  = o % (OUT_N * OUT_N);   // i*7+j
        const int i  = l / OUT_N;
        const int j  = l % OUT_N;
        const int xs = (j * w) / OUT_N;                  // rel. to x1
        const int xe = ((j + 1) * w + OUT_N - 1) / OUT_N;
        float m = -INFINITY;
        for (int dx = xs; dx < xe; ++dx) {
            m = fmaxf(m, tw[wc][i][dx]);
        }
        const int cc = cg * CPB + wc;
        out[((size_t)r * C + cc) * (OUT_N * OUT_N) + l] = m;
    }
}

extern "C" void kernel_launch(void* const* d_in, const int* in_sizes, int n_in,
                              void* d_out, int out_size, void* d_ws, size_t ws_size,
                              hipStream_t stream)
{
    const float* fm = (const float*)d_in[0];
    const int* rois = (const int*)d_in[1];
    float* out      = (float*)d_out;

    const int R = in_sizes[1] / 5;                        // 192
    const int C = out_size / (R * OUT_N * OUT_N);         // 256
    const int H = 50;
    const int W = 50;

    const int grid = R * (C / CPB);                       // 3072
    roicrop_kernel<<<grid, 256, 0, stream>>>(fm, rois, out, R, C, H, W);
}